// Round 7
// baseline (250.302 us; speedup 1.0000x reference)
//
#include <hip/hip_runtime.h>

typedef __attribute__((ext_vector_type(8))) short short8;
typedef __attribute__((ext_vector_type(4))) short short4v;
typedef __attribute__((ext_vector_type(4))) float floatx4;

#define NWSIDE 14
#define HLEN   56
#define DM     256

// Per-window LDS (bf16 elems): Q[16][264] @0, K[16][264] @4224.
// x-staging overlays Q; VT[256][16] overlays K after phase 4 (S^T) consumes it.
#define QK_STRIDE 264
#define K_OFF     4224
#define VT_OFF    4224
#define WINB      8448           // elems per window; 2 windows = 33792 B -> 4 blocks/CU

static __device__ __forceinline__ unsigned int f2bfu(float f) {
    unsigned int u = __float_as_uint(f);
    return (u + 0x7fffu + ((u >> 16) & 1u)) >> 16;    // RNE
}
static __device__ __forceinline__ unsigned short f2bf(float f) {
    return (unsigned short)f2bfu(f);
}

// fragment index (units of 512 elems) within a wave's 96KB weight region, for
// global fragment counter G in [0,96): pass A (Q/K tiles) G<64, pass B (V) G>=64.
static __device__ __forceinline__ int wfrag_off(int G) {
    if (G < 64) { const int pi = G >> 3, ks = G & 7; return 48 * (pi >> 2) + 8 * (pi & 3) + ks; }
    const int Gb = G - 64, pi = Gb >> 3, ks = Gb & 7;
    return 48 * (pi >> 1) + 32 + 8 * (pi & 1) + ks;
}

// prep: fragment-ordered weights (unchanged layout).
// WtF[((t*8 + ks)*64 + lane)*8 + j] = W[k][c],  where
//   col' = t*16 + (lane&15), k = ks*32 + (lane>>4)*8 + j,
//   c = h*96 + e*3 + sect  for  col' = h*96 + sect*32 + e.
__global__ void swin_prep(const float* __restrict__ W, const float* __restrict__ bias,
                          unsigned short* __restrict__ Wt, float* __restrict__ bperm) {
    const int k = blockIdx.x;                       // 0..255
    const int ks = k >> 5, lq = (k >> 3) & 3, j = k & 7;
    #pragma unroll
    for (int it = 0; it < 3; ++it) {
        const int c = it * 256 + threadIdx.x;       // 0..767, coalesced read
        const float w = W[(size_t)k * 768 + c];
        const int h = c / 96, r = c - h * 96;
        const int e = r / 3, sect = r - e * 3;
        const int cp = h * 96 + sect * 32 + e;      // col'
        const int t = cp >> 4, lrow = cp & 15;
        Wt[(size_t)(((t * 8 + ks) * 64 + lq * 16 + lrow) << 3) + j] = f2bf(w);
        if (k == 0) bperm[cp] = bias[c];
    }
}

// 3136 blocks (32 b x 98 pairs) x 256 threads (4 waves). 2 windows/block.
// VT-overlay LDS (33.8KB) + <=128 unified regs/wave -> 4 blocks/CU = 16 waves/CU.
__global__ __launch_bounds__(256, 4)
void swin_mfma(const float* __restrict__ x,
               const unsigned short* __restrict__ Wt,
               const float* __restrict__ bperm,
               float* __restrict__ out) {
    __shared__ __align__(16) unsigned short lds[2 * WINB];   // 33792 B

    const int b    = blockIdx.x / 98;
    const int g    = blockIdx.x % 98;           // windows 2g, 2g+1
    const int tid  = threadIdx.x;
    const int wv   = tid >> 6;
    const int lane = tid & 63;
    const int lrow = lane & 15;
    const int lq   = lane >> 4;
    const float scale = 0.17677669529663687f;   // 1/sqrt(32)
    const floatx4 zf = {0.f, 0.f, 0.f, 0.f};

    // cooperative-phase mapping: thread -> (window u2, token tk, segment sg)
    const int u2 = tid >> 7, tk = (tid >> 3) & 15, sg = tid & 7;
    const int ww2 = g * 2 + u2;
    const int wi2 = ww2 / NWSIDE, wj2 = ww2 % NWSIDE;
    const int gr2 = (wi2 * 4 + (tk >> 2) + 2) % HLEN;
    const int gc2 = (wj2 * 4 + (tk & 3) + 2) % HLEN;
    const size_t rowoff = ((size_t)(b * 3136 + gr2 * 56 + gc2)) * DM;

    // ---- phase 1: cooperative x load (contiguous 1KB token rows) -> bf16 LDS ----
    {
        const floatx4* xr = (const floatx4*)(x + rowoff);
        unsigned short* xd = &lds[u2 * WINB + tk * QK_STRIDE];
        #pragma unroll
        for (int j = 0; j < 8; ++j) {
            floatx4 f = xr[sg + 8 * j];          // 128B contiguous per 8 lanes
            short4v p;
            p[0] = (short)f2bf(f[0]); p[1] = (short)f2bf(f[1]);
            p[2] = (short)f2bf(f[2]); p[3] = (short)f2bf(f[3]);
            *(short4v*)&xd[(sg + 8 * j) * 4] = p;
        }
    }
    __syncthreads();

    // wave-base into fragment-ordered weights (wave wv owns col-tiles 12wv..12wv+11)
    const unsigned short* wbase = Wt + (size_t)(96 * wv) * 512 + (size_t)(lane * 8);

    // prologue: depth-4 rotating prefetch, frags G=0..3 fly across phase-2 LDS reads
    short8 Ab[4];
    #pragma unroll
    for (int f = 0; f < 4; ++f)
        Ab[f] = *(const short8*)(wbase + (wfrag_off(f) << 9));

    // ---- phase 2: B-fragments for both windows from LDS (b128) ----
    short8 xf[2][8];
    #pragma unroll
    for (int u = 0; u < 2; ++u)
        #pragma unroll
        for (int ks = 0; ks < 8; ++ks)
            xf[u][ks] = *(const short8*)&lds[u * WINB + lrow * QK_STRIDE + ks * 32 + lq * 8];
    __syncthreads();   // x-staging dead; Q region reusable

    // ---- pass A: Q/K tiles (8 per wave), depth-4 pipelined fragment stream ----
    // pi (0..7): t = 12wv + 6*(pi>>2) + (pi&3); h = 2wv + (pi>>2),
    // sect = (pi>>1)&1, e0 = (pi&1)*16.
    floatx4 acc0, acc1;
    #pragma unroll
    for (int f = 0; f < 64; ++f) {
        const int pi = f >> 3, ks = f & 7;
        if (ks == 0) {
            const int t = 12 * wv + 6 * (pi >> 2) + (pi & 3);
            floatx4 bv = *(const floatx4*)&bperm[t * 16 + lq * 4];
            acc0 = bv; acc1 = bv;
        }
        const short8 a = Ab[f & 3];
        Ab[f & 3] = *(const short8*)(wbase + (wfrag_off(f + 4) << 9));  // G=4..67
        acc0 = __builtin_amdgcn_mfma_f32_16x16x32_bf16(a, xf[0][ks], acc0, 0, 0, 0);
        acc1 = __builtin_amdgcn_mfma_f32_16x16x32_bf16(a, xf[1][ks], acc1, 0, 0, 0);
        if (ks == 7) {
            const int h    = 2 * wv + (pi >> 2);
            const int sect = (pi >> 1) & 1;
            const int e0   = (pi & 1) * 16;
            const int base = (sect ? K_OFF : 0) + lrow * QK_STRIDE + h * 32 + e0 + lq * 4;
            short4v p0, p1;
            p0[0] = (short)f2bf(acc0[0]); p0[1] = (short)f2bf(acc0[1]);
            p0[2] = (short)f2bf(acc0[2]); p0[3] = (short)f2bf(acc0[3]);
            p1[0] = (short)f2bf(acc1[0]); p1[1] = (short)f2bf(acc1[1]);
            p1[2] = (short)f2bf(acc1[2]); p1[3] = (short)f2bf(acc1[3]);
            *(short4v*)&lds[base]        = p0;
            *(short4v*)&lds[WINB + base] = p1;
        }
    }
    // pass A's rotating prefetch already left G=64..67 (V tile pi=0) in Ab[0..3]
    __syncthreads();   // Q/K visible

    // ---- phase 4: S^T (all Q/K reads happen here) ----
    const int u     = wv >> 1;
    const int hbase = (wv & 1) * 4;
    const int ww = g * 2 + u;
    const int wi = ww / NWSIDE, wj = ww % NWSIDE;
    const bool lastrow = (wi == NWSIDE - 1);
    const bool lastcol = (wj == NWSIDE - 1);
    const unsigned short* wl = lds + u * WINB;
    const bool mrow = lastrow && ((lrow >= 8) != (lq >= 2));
    const bool mc   = ((lrow & 3) >= 2);
    const int vtq = (lq & 1) * 8;

    floatx4 ST[4];
    #pragma unroll
    for (int hh = 0; hh < 4; ++hh) {
        const int h = hbase + hh;
        short8 Ak = *(const short8*)&wl[K_OFF + lrow * QK_STRIDE + h * 32 + lq * 8];
        short8 Bq = *(const short8*)&wl[lrow * QK_STRIDE + h * 32 + lq * 8];
        ST[hh] = __builtin_amdgcn_mfma_f32_16x16x32_bf16(Ak, Bq, zf, 0, 0, 0);
    }
    __syncthreads();   // K reads drained; VT overlay safe

    // ---- pass B: V tiles (4 per wave) -> VT over the K region ----
    // pi (0..3): t = 12wv + 6*(pi>>1) + 4 + (pi&1); h = 2wv + (pi>>1), e0 = (pi&1)*16.
    #pragma unroll
    for (int f = 0; f < 32; ++f) {
        const int pi = f >> 3, ks = f & 7;
        if (ks == 0) {
            const int t = 12 * wv + 6 * (pi >> 1) + 4 + (pi & 1);
            floatx4 bv = *(const floatx4*)&bperm[t * 16 + lq * 4];
            acc0 = bv; acc1 = bv;
        }
        const short8 a = Ab[f & 3];
        if (f < 28)
            Ab[f & 3] = *(const short8*)(wbase + (wfrag_off(68 + f) << 9));  // G=68..95
        acc0 = __builtin_amdgcn_mfma_f32_16x16x32_bf16(a, xf[0][ks], acc0, 0, 0, 0);
        acc1 = __builtin_amdgcn_mfma_f32_16x16x32_bf16(a, xf[1][ks], acc1, 0, 0, 0);
        if (ks == 7) {
            const int h  = 2 * wv + (pi >> 1);
            const int e0 = (pi & 1) * 16;
            #pragma unroll
            for (int i = 0; i < 4; ++i) {
                const int rowe = h * 32 + e0 + lq * 4 + i;
                lds[VT_OFF + rowe * 16 + lrow]        = f2bf(acc0[i]);
                lds[WINB + VT_OFF + rowe * 16 + lrow] = f2bf(acc1[i]);
            }
        }
    }
    __syncthreads();   // VT visible

    // ---- phase 5: softmax + PV, O -> global directly ----
    const int gr5 = (wi * 4 + (lrow >> 2) + 2) % HLEN;
    const int gc5 = (wj * 4 + (lrow & 3) + 2) % HLEN;
    float* op = out + ((size_t)(b * 3136 + gr5 * 56 + gc5)) * DM;

    #pragma unroll
    for (int hh = 0; hh < 4; ++hh) {
        const int h = hbase + hh;
        // lane holds S^T[s = lq*4+i][t = lrow]
        float ev[4];
        #pragma unroll
        for (int i = 0; i < 4; ++i) {
            bool m = mrow || (lastcol && (mc != (i >= 2)));
            ev[i] = __expf(m ? -1e30f : ST[hh][i] * scale);
        }
        float rs = (ev[0] + ev[1]) + (ev[2] + ev[3]);
        rs += __shfl_xor(rs, 16);
        rs += __shfl_xor(rs, 32);
        const float inv = 1.0f / rs;
        const unsigned int d0 = f2bfu(ev[0] * inv) | (f2bfu(ev[1] * inv) << 16);
        const unsigned int d1 = f2bfu(ev[2] * inv) | (f2bfu(ev[3] * inv) << 16);
        // P^T B-fragment: lane needs s = lq*8 + j (j 0..7); zero for lq>=2
        const int src0 = lrow + ((lq & 1) << 5);
        int b0 = __shfl((int)d0, src0);
        int b1 = __shfl((int)d1, src0);
        int b2 = __shfl((int)d0, src0 + 16);
        int b3 = __shfl((int)d1, src0 + 16);
        if (lq >= 2) { b0 = 0; b1 = 0; b2 = 0; b3 = 0; }
        union { int i4[4]; short8 s8; } bp;
        bp.i4[0] = b0; bp.i4[1] = b1; bp.i4[2] = b2; bp.i4[3] = b3;
        #pragma unroll
        for (int eb = 0; eb < 2; ++eb) {
            short8 Av = *(const short8*)&wl[VT_OFF + (h * 32 + eb * 16 + lrow) * 16 + vtq];
            floatx4 O = __builtin_amdgcn_mfma_f32_16x16x32_bf16(Av, bp.s8, zf, 0, 0, 0);
            // lane holds O[t=lrow][e = eb*16 + lq*4 + i]; wave writes 16 tokens x 64B
            *(floatx4*)&op[h * 32 + eb * 16 + lq * 4] = O;
        }
    }
}

extern "C" void kernel_launch(void* const* d_in, const int* in_sizes, int n_in,
                              void* d_out, int out_size, void* d_ws, size_t ws_size,
                              hipStream_t stream) {
    const float* x    = (const float*)d_in[0];
    const float* W    = (const float*)d_in[1];
    const float* bias = (const float*)d_in[2];
    float* out = (float*)d_out;
    (void)in_sizes; (void)n_in; (void)out_size; (void)ws_size;

    unsigned short* Wt = (unsigned short*)d_ws;                // 393216 B (fragment order)
    float* bperm = (float*)((char*)d_ws + 768 * 256 * 2);      // +3072 B

    swin_prep<<<256, 256, 0, stream>>>(W, bias, Wt, bperm);
    swin_mfma<<<32 * 98, 256, 0, stream>>>(x, Wt, bperm, out);
}

// Round 9
// 217.757 us; speedup vs baseline: 1.1495x; 1.1495x over previous
//
#include <hip/hip_runtime.h>

typedef __attribute__((ext_vector_type(8))) short short8;
typedef __attribute__((ext_vector_type(4))) short short4v;
typedef __attribute__((ext_vector_type(4))) float floatx4;

#define NWSIDE 14
#define HLEN   56
#define DM     256

// Per-window LDS (bf16 elems): Q[16][264] @0, K[16][264] @4224, VT[256][16] @8448
// xs (staged x, bf16) overlays the Q region; O (fp32) overlays Q+K after attention reads.
#define QK_STRIDE 264
#define K_OFF     4224
#define VT_OFF    8448
#define WINELEMS  12544          // x2 windows = 25088 elems = 50176 B -> 3 blocks/CU
#define OW_F      6272           // fp32 stride per window for O staging (25088B/4)

static __device__ __forceinline__ unsigned int f2bfu(float f) {
    unsigned int u = __float_as_uint(f);
    return (u + 0x7fffu + ((u >> 16) & 1u)) >> 16;    // RNE
}
static __device__ __forceinline__ unsigned short f2bf(float f) {
    return (unsigned short)f2bfu(f);
}

// prep: fragment-ordered weights.
// WtF[((t*8 + ks)*64 + lane)*8 + j] = W[k][c],  where
//   col' = t*16 + (lane&15), k = ks*32 + (lane>>4)*8 + j,
//   c = h*96 + e*3 + sect  for  col' = h*96 + sect*32 + e.
__global__ void swin_prep(const float* __restrict__ W, const float* __restrict__ bias,
                          unsigned short* __restrict__ Wt, float* __restrict__ bperm) {
    const int k = blockIdx.x;                       // 0..255
    const int ks = k >> 5, lq = (k >> 3) & 3, j = k & 7;
    #pragma unroll
    for (int it = 0; it < 3; ++it) {
        const int c = it * 256 + threadIdx.x;       // 0..767, coalesced read
        const float w = W[(size_t)k * 768 + c];
        const int h = c / 96, r = c - h * 96;
        const int e = r / 3, sect = r - e * 3;
        const int cp = h * 96 + sect * 32 + e;      // col'
        const int t = cp >> 4, lrow = cp & 15;
        Wt[(size_t)(((t * 8 + ks) * 64 + lq * 16 + lrow) << 3) + j] = f2bf(w);
        if (k == 0) bperm[cp] = bias[c];
    }
}

// 3136 blocks (32 b x 98 pairs) x 256 threads (4 waves). 2 windows/block, 3 blocks/CU.
// Structure: verified-best R1 (O-staged stores) + hoisted prologue + ping-pong weights.
__global__ __launch_bounds__(256, 3)
void swin_mfma(const float* __restrict__ x,
               const unsigned short* __restrict__ Wt,
               const float* __restrict__ bperm,
               float* __restrict__ out) {
    __shared__ __align__(16) unsigned short lds[2 * WINELEMS];

    const int b    = blockIdx.x / 98;
    const int g    = blockIdx.x % 98;           // windows 2g, 2g+1
    const int tid  = threadIdx.x;
    const int wv   = tid >> 6;
    const int lane = tid & 63;
    const int lrow = lane & 15;
    const int lq   = lane >> 4;
    const float scale = 0.17677669529663687f;   // 1/sqrt(32)
    const floatx4 zf = {0.f, 0.f, 0.f, 0.f};

    // cooperative-phase mapping: thread -> (window u2, token tk, segment sg)
    const int u2 = tid >> 7, tk = (tid >> 3) & 15, sg = tid & 7;
    const int ww2 = g * 2 + u2;
    const int wi2 = ww2 / NWSIDE, wj2 = ww2 % NWSIDE;
    const int gr2 = (wi2 * 4 + (tk >> 2) + 2) % HLEN;
    const int gc2 = (wj2 * 4 + (tk & 3) + 2) % HLEN;
    const size_t rowoff = ((size_t)(b * 3136 + gr2 * 56 + gc2)) * DM;

    // ---- phase 1: issue x loads (HBM/L3) into regs FIRST ----
    floatx4 xv[8];
    {
        const floatx4* xr = (const floatx4*)(x + rowoff);
        #pragma unroll
        for (int j = 0; j < 8; ++j) xv[j] = xr[sg + 8 * j];   // 128B contig per 8 lanes
    }

    // weight + bias prologue for tiles 0 and 1 of this wave, issued while x in flight
    const unsigned short* wfp = Wt + (size_t)(wv * 12) * 4096 + (size_t)lane * 8;
    short8 Ab[2][8];
    floatx4 bv[2];
    #pragma unroll
    for (int ks = 0; ks < 8; ++ks) Ab[0][ks] = *(const short8*)(wfp + ks * 512);
    bv[0] = *(const floatx4*)&bperm[(wv * 12 + 0) * 16 + lq * 4];
    #pragma unroll
    for (int ks = 0; ks < 8; ++ks) Ab[1][ks] = *(const short8*)(wfp + 4096 + ks * 512);
    bv[1] = *(const floatx4*)&bperm[(wv * 12 + 1) * 16 + lq * 4];

    // convert staged x -> bf16 LDS (contiguous 1KB token rows)
    {
        unsigned short* xd = &lds[u2 * WINELEMS + tk * QK_STRIDE];
        #pragma unroll
        for (int j = 0; j < 8; ++j) {
            short4v p;
            p[0] = (short)f2bf(xv[j][0]); p[1] = (short)f2bf(xv[j][1]);
            p[2] = (short)f2bf(xv[j][2]); p[3] = (short)f2bf(xv[j][3]);
            *(short4v*)&xd[(sg + 8 * j) * 4] = p;
        }
    }
    __syncthreads();

    // ---- phase 2: build MFMA B-fragments from LDS (conflict-free b128) ----
    short8 xf[2][8];
    #pragma unroll
    for (int u = 0; u < 2; ++u)
        #pragma unroll
        for (int ks = 0; ks < 8; ++ks)
            xf[u][ks] = *(const short8*)&lds[u * WINELEMS + lrow * QK_STRIDE + ks * 32 + lq * 8];
    __syncthreads();   // xs dead; Q region reusable

    // ---- phase 3: GEMM qkv^T, ping-pong weight buffers (all indices compile-time) ----
    #pragma unroll
    for (int n = 0; n < 12; ++n) {
        const int t    = wv * 12 + n;
        const int col0 = t * 16;

        floatx4 acc0 = bv[n & 1], acc1 = bv[n & 1];
        #pragma unroll
        for (int ks = 0; ks < 8; ++ks) {
            acc0 = __builtin_amdgcn_mfma_f32_16x16x32_bf16(Ab[n & 1][ks], xf[0][ks], acc0, 0, 0, 0);
            acc1 = __builtin_amdgcn_mfma_f32_16x16x32_bf16(Ab[n & 1][ks], xf[1][ks], acc1, 0, 0, 0);
        }

        // prefetch tile n+2 into the buffer just consumed
        if (n < 10) {
            const unsigned short* wnp = wfp + (size_t)(n + 2) * 4096;
            #pragma unroll
            for (int ks = 0; ks < 8; ++ks) Ab[n & 1][ks] = *(const short8*)(wnp + ks * 512);
            bv[n & 1] = *(const floatx4*)&bperm[(t + 2) * 16 + lq * 4];
        }

        const int h    = t / 6;
        const int r    = col0 - h * 96;
        const int sect = r >> 5;
        const int e0   = r & 31;
        // lane holds qkv[tok=lrow][col0 + lq*4 + i]
        if (sect < 2) {
            const int base = (sect ? K_OFF : 0) + lrow * QK_STRIDE + h * 32 + e0 + lq * 4;
            short4v p0, p1;
            p0[0] = (short)f2bf(acc0[0]); p0[1] = (short)f2bf(acc0[1]);
            p0[2] = (short)f2bf(acc0[2]); p0[3] = (short)f2bf(acc0[3]);
            p1[0] = (short)f2bf(acc1[0]); p1[1] = (short)f2bf(acc1[1]);
            p1[2] = (short)f2bf(acc1[2]); p1[3] = (short)f2bf(acc1[3]);
            *(short4v*)&lds[base]            = p0;
            *(short4v*)&lds[WINELEMS + base] = p1;
        } else {
            #pragma unroll
            for (int i = 0; i < 4; ++i) {
                const int rowe = h * 32 + e0 + lq * 4 + i;
                lds[VT_OFF + rowe * 16 + lrow]            = f2bf(acc0[i]);
                lds[WINELEMS + VT_OFF + rowe * 16 + lrow] = f2bf(acc1[i]);
            }
        }
    }
    __syncthreads();

    // ---- phase 4: S^T precompute (all Q/K reads happen here) ----
    const int u     = wv >> 1;
    const int hbase = (wv & 1) * 4;
    const int ww = g * 2 + u;
    const int wi = ww / NWSIDE, wj = ww % NWSIDE;
    const bool lastrow = (wi == NWSIDE - 1);
    const bool lastcol = (wj == NWSIDE - 1);
    const unsigned short* wl = lds + u * WINELEMS;
    const bool mrow = lastrow && ((lrow >= 8) != (lq >= 2));
    const bool mc   = ((lrow & 3) >= 2);
    const int vtq = (lq & 1) * 8;

    floatx4 ST[4];
    #pragma unroll
    for (int hh = 0; hh < 4; ++hh) {
        const int h = hbase + hh;
        short8 Ak = *(const short8*)&wl[K_OFF + lrow * QK_STRIDE + h * 32 + lq * 8];
        short8 Bq = *(const short8*)&wl[lrow * QK_STRIDE + h * 32 + lq * 8];
        ST[hh] = __builtin_amdgcn_mfma_f32_16x16x32_bf16(Ak, Bq, zf, 0, 0, 0);
    }
    __syncthreads();   // Q/K dead; O staging may overwrite

    // ---- phase 5: softmax + PV, O -> LDS (fp32, over old Q+K region) ----
    float* Of = (float*)lds;
    #pragma unroll
    for (int hh = 0; hh < 4; ++hh) {
        const int h = hbase + hh;
        // lane holds S^T[s = lq*4+i][t = lrow]
        float ev[4];
        #pragma unroll
        for (int i = 0; i < 4; ++i) {
            bool m = mrow || (lastcol && (mc != (i >= 2)));
            ev[i] = __expf(m ? -1e30f : ST[hh][i] * scale);
        }
        float rs = (ev[0] + ev[1]) + (ev[2] + ev[3]);
        rs += __shfl_xor(rs, 16);
        rs += __shfl_xor(rs, 32);
        const float inv = 1.0f / rs;
        const unsigned int d0 = f2bfu(ev[0] * inv) | (f2bfu(ev[1] * inv) << 16);
        const unsigned int d1 = f2bfu(ev[2] * inv) | (f2bfu(ev[3] * inv) << 16);
        // P^T B-fragment: lane needs s = lq*8 + j (j 0..7); zero for lq>=2
        const int src0 = lrow + ((lq & 1) << 5);
        int b0 = __shfl((int)d0, src0);
        int b1 = __shfl((int)d1, src0);
        int b2 = __shfl((int)d0, src0 + 16);
        int b3 = __shfl((int)d1, src0 + 16);
        if (lq >= 2) { b0 = 0; b1 = 0; b2 = 0; b3 = 0; }
        union { int i4[4]; short8 s8; } bp;
        bp.i4[0] = b0; bp.i4[1] = b1; bp.i4[2] = b2; bp.i4[3] = b3;
        #pragma unroll
        for (int eb = 0; eb < 2; ++eb) {
            short8 Av = *(const short8*)&wl[VT_OFF + (h * 32 + eb * 16 + lrow) * 16 + vtq];
            floatx4 O = __builtin_amdgcn_mfma_f32_16x16x32_bf16(Av, bp.s8, zf, 0, 0, 0);
            // lane holds O[t=lrow][e = eb*16 + lq*4 + i]
            *(floatx4*)&Of[u * OW_F + lrow * QK_STRIDE + h * 32 + eb * 16 + lq * 4] = O;
        }
    }
    __syncthreads();

    // ---- phase 6: cooperative store (contiguous 1KB token rows) ----
    {
        float* op = out + rowoff;
        const float* Os = &Of[u2 * OW_F + tk * QK_STRIDE];
        #pragma unroll
        for (int j = 0; j < 8; ++j)
            *(floatx4*)&op[(sg + 8 * j) * 4] = *(const floatx4*)&Os[(sg + 8 * j) * 4];
    }
}

extern "C" void kernel_launch(void* const* d_in, const int* in_sizes, int n_in,
                              void* d_out, int out_size, void* d_ws, size_t ws_size,
                              hipStream_t stream) {
    const float* x    = (const float*)d_in[0];
    const float* W    = (const float*)d_in[1];
    const float* bias = (const float*)d_in[2];
    float* out = (float*)d_out;
    (void)in_sizes; (void)n_in; (void)out_size; (void)ws_size;

    unsigned short* Wt = (unsigned short*)d_ws;                // 393216 B (fragment order)
    float* bperm = (float*)((char*)d_ws + 768 * 256 * 2);      // +3072 B

    swin_prep<<<256, 256, 0, stream>>>(W, bias, Wt, bperm);
    swin_mfma<<<32 * 98, 256, 0, stream>>>(x, Wt, bperm, out);
}

// Round 13
// 216.918 us; speedup vs baseline: 1.1539x; 1.0039x over previous
//
#include <hip/hip_runtime.h>

typedef __attribute__((ext_vector_type(8))) short short8;
typedef __attribute__((ext_vector_type(4))) short short4v;
typedef __attribute__((ext_vector_type(4))) float floatx4;

#define NWSIDE 14
#define HLEN   56
#define DM     256

// Per-window LDS (bf16 elems): Q[16][264] @0, K[16][264] @4224, VT[256][16] @8448
// xs (staged x, bf16) overlays the Q region; O (fp32) overlays Q+K after attention reads.
#define QK_STRIDE 264
#define K_OFF     4224
#define VT_OFF    8448
#define WINELEMS  12544          // x2 windows = 25088 elems = 50176 B -> 3 blocks/CU
#define OW_F      6272           // fp32 stride per window for O staging (25088B/4)

static __device__ __forceinline__ unsigned int f2bfu(float f) {
    unsigned int u = __float_as_uint(f);
    return (u + 0x7fffu + ((u >> 16) & 1u)) >> 16;    // RNE
}
static __device__ __forceinline__ unsigned short f2bf(float f) {
    return (unsigned short)f2bfu(f);
}

// prep: fragment-ordered weights.
// WtF[((t*8 + ks)*64 + lane)*8 + j] = W[k][c],  where
//   col' = t*16 + (lane&15), k = ks*32 + (lane>>4)*8 + j,
//   c = h*96 + e*3 + sect  for  col' = h*96 + sect*32 + e.
__global__ void swin_prep(const float* __restrict__ W, const float* __restrict__ bias,
                          unsigned short* __restrict__ Wt, float* __restrict__ bperm) {
    const int k = blockIdx.x;                       // 0..255
    const int ks = k >> 5, lq = (k >> 3) & 3, j = k & 7;
    #pragma unroll
    for (int it = 0; it < 3; ++it) {
        const int c = it * 256 + threadIdx.x;       // 0..767, coalesced read
        const float w = W[(size_t)k * 768 + c];
        const int h = c / 96, r = c - h * 96;
        const int e = r / 3, sect = r - e * 3;
        const int cp = h * 96 + sect * 32 + e;      // col'
        const int t = cp >> 4, lrow = cp & 15;
        Wt[(size_t)(((t * 8 + ks) * 64 + lq * 16 + lrow) << 3) + j] = f2bf(w);
        if (k == 0) bperm[cp] = bias[c];
    }
}

// 3136 blocks (32 b x 98 pairs) x 256 threads (4 waves). 2 windows/block, 3 blocks/CU.
// R9 structure with split prologue: tile-0 weights overlap x loads; tile-1 weights
// issue after xv dies (conversion done), killing the ~12B/thread scratch spill.
__global__ __launch_bounds__(256, 3)
void swin_mfma(const float* __restrict__ x,
               const unsigned short* __restrict__ Wt,
               const float* __restrict__ bperm,
               float* __restrict__ out) {
    __shared__ __align__(16) unsigned short lds[2 * WINELEMS];

    const int b    = blockIdx.x / 98;
    const int g    = blockIdx.x % 98;           // windows 2g, 2g+1
    const int tid  = threadIdx.x;
    const int wv   = tid >> 6;
    const int lane = tid & 63;
    const int lrow = lane & 15;
    const int lq   = lane >> 4;
    const float scale = 0.17677669529663687f;   // 1/sqrt(32)
    const floatx4 zf = {0.f, 0.f, 0.f, 0.f};

    // cooperative-phase mapping: thread -> (window u2, token tk, segment sg)
    const int u2 = tid >> 7, tk = (tid >> 3) & 15, sg = tid & 7;
    const int ww2 = g * 2 + u2;
    const int wi2 = ww2 / NWSIDE, wj2 = ww2 % NWSIDE;
    const int gr2 = (wi2 * 4 + (tk >> 2) + 2) % HLEN;
    const int gc2 = (wj2 * 4 + (tk & 3) + 2) % HLEN;
    const size_t rowoff = ((size_t)(b * 3136 + gr2 * 56 + gc2)) * DM;

    // ---- phase 1: issue x loads (HBM/L3) into regs FIRST ----
    floatx4 xv[8];
    {
        const floatx4* xr = (const floatx4*)(x + rowoff);
        #pragma unroll
        for (int j = 0; j < 8; ++j) xv[j] = xr[sg + 8 * j];   // 128B contig per 8 lanes
    }

    // tile-0 weights + bias issued while x is in flight (xv still live; small set)
    const unsigned short* wfp = Wt + (size_t)(wv * 12) * 4096 + (size_t)lane * 8;
    short8 Ab[2][8];
    floatx4 bv[2];
    #pragma unroll
    for (int ks = 0; ks < 8; ++ks) Ab[0][ks] = *(const short8*)(wfp + ks * 512);
    bv[0] = *(const floatx4*)&bperm[(wv * 12 + 0) * 16 + lq * 4];

    // convert staged x -> bf16 LDS (contiguous 1KB token rows); xv dies here
    {
        unsigned short* xd = &lds[u2 * WINELEMS + tk * QK_STRIDE];
        #pragma unroll
        for (int j = 0; j < 8; ++j) {
            short4v p;
            p[0] = (short)f2bf(xv[j][0]); p[1] = (short)f2bf(xv[j][1]);
            p[2] = (short)f2bf(xv[j][2]); p[3] = (short)f2bf(xv[j][3]);
            *(short4v*)&xd[(sg + 8 * j) * 4] = p;
        }
    }

    // tile-1 weights + bias: xv registers are dead, so no pressure spike;
    // the loads fly across the barrier drain + phase-2 LDS reads.
    #pragma unroll
    for (int ks = 0; ks < 8; ++ks) Ab[1][ks] = *(const short8*)(wfp + 4096 + ks * 512);
    bv[1] = *(const floatx4*)&bperm[(wv * 12 + 1) * 16 + lq * 4];

    __syncthreads();

    // ---- phase 2: build MFMA B-fragments from LDS (conflict-free b128) ----
    short8 xf[2][8];
    #pragma unroll
    for (int u = 0; u < 2; ++u)
        #pragma unroll
        for (int ks = 0; ks < 8; ++ks)
            xf[u][ks] = *(const short8*)&lds[u * WINELEMS + lrow * QK_STRIDE + ks * 32 + lq * 8];
    __syncthreads();   // xs dead; Q region reusable

    // ---- phase 3: GEMM qkv^T, ping-pong weight buffers (all indices compile-time) ----
    #pragma unroll
    for (int n = 0; n < 12; ++n) {
        const int t    = wv * 12 + n;
        const int col0 = t * 16;

        floatx4 acc0 = bv[n & 1], acc1 = bv[n & 1];
        #pragma unroll
        for (int ks = 0; ks < 8; ++ks) {
            acc0 = __builtin_amdgcn_mfma_f32_16x16x32_bf16(Ab[n & 1][ks], xf[0][ks], acc0, 0, 0, 0);
            acc1 = __builtin_amdgcn_mfma_f32_16x16x32_bf16(Ab[n & 1][ks], xf[1][ks], acc1, 0, 0, 0);
        }

        // prefetch tile n+2 into the buffer just consumed
        if (n < 10) {
            const unsigned short* wnp = wfp + (size_t)(n + 2) * 4096;
            #pragma unroll
            for (int ks = 0; ks < 8; ++ks) Ab[n & 1][ks] = *(const short8*)(wnp + ks * 512);
            bv[n & 1] = *(const floatx4*)&bperm[(t + 2) * 16 + lq * 4];
        }

        const int h    = t / 6;
        const int r    = col0 - h * 96;
        const int sect = r >> 5;
        const int e0   = r & 31;
        // lane holds qkv[tok=lrow][col0 + lq*4 + i]
        if (sect < 2) {
            const int base = (sect ? K_OFF : 0) + lrow * QK_STRIDE + h * 32 + e0 + lq * 4;
            short4v p0, p1;
            p0[0] = (short)f2bf(acc0[0]); p0[1] = (short)f2bf(acc0[1]);
            p0[2] = (short)f2bf(acc0[2]); p0[3] = (short)f2bf(acc0[3]);
            p1[0] = (short)f2bf(acc1[0]); p1[1] = (short)f2bf(acc1[1]);
            p1[2] = (short)f2bf(acc1[2]); p1[3] = (short)f2bf(acc1[3]);
            *(short4v*)&lds[base]            = p0;
            *(short4v*)&lds[WINELEMS + base] = p1;
        } else {
            #pragma unroll
            for (int i = 0; i < 4; ++i) {
                const int rowe = h * 32 + e0 + lq * 4 + i;
                lds[VT_OFF + rowe * 16 + lrow]            = f2bf(acc0[i]);
                lds[WINELEMS + VT_OFF + rowe * 16 + lrow] = f2bf(acc1[i]);
            }
        }
    }
    __syncthreads();

    // ---- phase 4: S^T precompute (all Q/K reads happen here) ----
    const int u     = wv >> 1;
    const int hbase = (wv & 1) * 4;
    const int ww = g * 2 + u;
    const int wi = ww / NWSIDE, wj = ww % NWSIDE;
    const bool lastrow = (wi == NWSIDE - 1);
    const bool lastcol = (wj == NWSIDE - 1);
    const unsigned short* wl = lds + u * WINELEMS;
    const bool mrow = lastrow && ((lrow >= 8) != (lq >= 2));
    const bool mc   = ((lrow & 3) >= 2);
    const int vtq = (lq & 1) * 8;

    floatx4 ST[4];
    #pragma unroll
    for (int hh = 0; hh < 4; ++hh) {
        const int h = hbase + hh;
        short8 Ak = *(const short8*)&wl[K_OFF + lrow * QK_STRIDE + h * 32 + lq * 8];
        short8 Bq = *(const short8*)&wl[lrow * QK_STRIDE + h * 32 + lq * 8];
        ST[hh] = __builtin_amdgcn_mfma_f32_16x16x32_bf16(Ak, Bq, zf, 0, 0, 0);
    }
    __syncthreads();   // Q/K dead; O staging may overwrite

    // ---- phase 5: softmax + PV, O -> LDS (fp32, over old Q+K region) ----
    float* Of = (float*)lds;
    #pragma unroll
    for (int hh = 0; hh < 4; ++hh) {
        const int h = hbase + hh;
        // lane holds S^T[s = lq*4+i][t = lrow]
        float ev[4];
        #pragma unroll
        for (int i = 0; i < 4; ++i) {
            bool m = mrow || (lastcol && (mc != (i >= 2)));
            ev[i] = __expf(m ? -1e30f : ST[hh][i] * scale);
        }
        float rs = (ev[0] + ev[1]) + (ev[2] + ev[3]);
        rs += __shfl_xor(rs, 16);
        rs += __shfl_xor(rs, 32);
        const float inv = 1.0f / rs;
        const unsigned int d0 = f2bfu(ev[0] * inv) | (f2bfu(ev[1] * inv) << 16);
        const unsigned int d1 = f2bfu(ev[2] * inv) | (f2bfu(ev[3] * inv) << 16);
        // P^T B-fragment: lane needs s = lq*8 + j (j 0..7); zero for lq>=2
        const int src0 = lrow + ((lq & 1) << 5);
        int b0 = __shfl((int)d0, src0);
        int b1 = __shfl((int)d1, src0);
        int b2 = __shfl((int)d0, src0 + 16);
        int b3 = __shfl((int)d1, src0 + 16);
        if (lq >= 2) { b0 = 0; b1 = 0; b2 = 0; b3 = 0; }
        union { int i4[4]; short8 s8; } bp;
        bp.i4[0] = b0; bp.i4[1] = b1; bp.i4[2] = b2; bp.i4[3] = b3;
        #pragma unroll
        for (int eb = 0; eb < 2; ++eb) {
            short8 Av = *(const short8*)&wl[VT_OFF + (h * 32 + eb * 16 + lrow) * 16 + vtq];
            floatx4 O = __builtin_amdgcn_mfma_f32_16x16x32_bf16(Av, bp.s8, zf, 0, 0, 0);
            // lane holds O[t=lrow][e = eb*16 + lq*4 + i]
            *(floatx4*)&Of[u * OW_F + lrow * QK_STRIDE + h * 32 + eb * 16 + lq * 4] = O;
        }
    }
    __syncthreads();

    // ---- phase 6: cooperative store (contiguous 1KB token rows) ----
    {
        float* op = out + rowoff;
        const float* Os = &Of[u2 * OW_F + tk * QK_STRIDE];
        #pragma unroll
        for (int j = 0; j < 8; ++j)
            *(floatx4*)&op[(sg + 8 * j) * 4] = *(const floatx4*)&Os[(sg + 8 * j) * 4];
    }
}

extern "C" void kernel_launch(void* const* d_in, const int* in_sizes, int n_in,
                              void* d_out, int out_size, void* d_ws, size_t ws_size,
                              hipStream_t stream) {
    const float* x    = (const float*)d_in[0];
    const float* W    = (const float*)d_in[1];
    const float* bias = (const float*)d_in[2];
    float* out = (float*)d_out;
    (void)in_sizes; (void)n_in; (void)out_size; (void)ws_size;

    unsigned short* Wt = (unsigned short*)d_ws;                // 393216 B (fragment order)
    float* bperm = (float*)((char*)d_ws + 768 * 256 * 2);      // +3072 B

    swin_prep<<<256, 256, 0, stream>>>(W, bias, Wt, bperm);
    swin_mfma<<<32 * 98, 256, 0, stream>>>(x, Wt, bperm, out);
}